// Round 3
// baseline (9355.024 us; speedup 1.0000x reference)
//
#include <hip/hip_runtime.h>
#include <hip/hip_bf16.h>
#include <cstdint>

// ---------------------------------------------------------------------------
// SsLayer: outputs[2,B,T,OUT] (loc, softplus-scale) + state_out[B,NS]
//   ck_* : fp32 -> f16 conversions / layout prep (x, Bm^T, [C|D]^T, A slices)
//   gemm<256,0>: U = x @ Bm + b            (f16 MFMA, out f16 in ws)
//   scan       : s_{t+1} = tanh(u_t + s_t A)  4 WGs per chain (256 WGs total),
//                each WG holds A[:, 128-col slice] in 64 VGPRs/thread;
//                per-step cross-WG all-gather of state via L2 + flags
//   gemm<512,1>: loc = S@C + c ; scale = softplus(S@D + d)  (fp32 out)
// ---------------------------------------------------------------------------

typedef _Float16 f16;
typedef _Float16 f16x2 __attribute__((ext_vector_type(2)));
typedef _Float16 f16x4 __attribute__((ext_vector_type(4)));
typedef _Float16 f16x8 __attribute__((ext_vector_type(8)));
typedef float    f32x4 __attribute__((ext_vector_type(4)));

#define NS 512

// ws byte offsets (total ~129.4 MB). x16 shares the S16 region: x16 is dead
// after gemm1; scan then overwrites the region with S16.
#define OFF_S16   (0ull)            // 67,108,864   (S: [B*T, 512] f16)
#define OFF_X16   (0ull)            // 33,554,432   (x16 lives here during phase 1)
#define OFF_U16   (67108864ull)     // 67,108,864   (U: [B*T, 512] f16, bias added)
#define OFF_BMT   (134217728ull)    //    262,144   (Bm^T: [512][256] f16)
#define OFF_CDT   (134479872ull)    //    524,288   ([C|D]^T: [512][512] f16)
#define OFF_AP    (135004160ull)    //    524,288   (A slices, per-thread packed)
#define OFF_SBUF  (135528448ull)    //    131,072   (state exchange, 2-slot parity)
#define OFF_FLAG  (135659520ull)    //     16,384   (per-WG step flags, 64B apart)

#if defined(__has_builtin)
#  if __has_builtin(__builtin_amdgcn_fdot2)
#    define HAS_FDOT2 1
#  endif
#endif

__device__ __forceinline__ float fdot2f(unsigned a, unsigned s, float c) {
#ifdef HAS_FDOT2
  return __builtin_amdgcn_fdot2(__builtin_bit_cast(f16x2, a),
                                __builtin_bit_cast(f16x2, s), c, false);
#else
  f16x2 av = __builtin_bit_cast(f16x2, a);
  f16x2 sv = __builtin_bit_cast(f16x2, s);
  return c + (float)av[0] * (float)sv[0] + (float)av[1] * (float)sv[1];
#endif
}

__device__ __forceinline__ unsigned packh2(float a, float b) {
  f16x2 h; h[0] = (f16)a; h[1] = (f16)b;
  return __builtin_bit_cast(unsigned, h);
}

#define BCU(x) __builtin_bit_cast(unsigned, (x))

// ------------------------------ prep kernels -------------------------------

__global__ void ck_x(const float* __restrict__ xg, f16* __restrict__ x16) {
  int i = (blockIdx.x * 256 + threadIdx.x) * 4;
  float4 v = *(const float4*)(xg + i);
  f16x4 h; h[0] = (f16)v.x; h[1] = (f16)v.y; h[2] = (f16)v.z; h[3] = (f16)v.w;
  *(f16x4*)(x16 + i) = h;
}

__global__ void ck_bmt(const float* __restrict__ Bm, f16* __restrict__ BmT) {
  int g = blockIdx.x * 256 + threadIdx.x;   // 131072 = 512*256
  int n = g >> 8, k = g & 255;
  BmT[g] = (f16)Bm[k * 512 + n];            // BmT[n][k]
}

__global__ void ck_cdt(const float* __restrict__ C, const float* __restrict__ D,
                       f16* __restrict__ CDT) {
  int g = blockIdx.x * 256 + threadIdx.x;   // 262144 = 512*512
  int n = g >> 9, k = g & 511;
  float v = (n < 256) ? C[k * 256 + n] : D[k * 256 + (n - 256)];
  CDT[g] = (f16)v;                          // CDT[n][k], n<256 -> C, else D
}

// A slice layout for the split scan. WG w owns j in [w*128, w*128+128).
// Thread t (kg=t>>7, jl=t&127, j=w*128+jl) holds 64 packed dwords i=0..63:
//   pack(A[kg*128+2i][j], A[kg*128+2i+1][j])
// stored as float4 c=0..15 at AP4[(w*512+t)*16 + c]  (dword d=i&3, i=c*4+d).
__global__ void ck_a(const float* __restrict__ Ag, unsigned* __restrict__ AP) {
  int g = blockIdx.x * 256 + threadIdx.x;   // 131072 dwords = full A packed
  int i = g & 63;
  int t = (g >> 6) & 511;
  int w = g >> 15;
  int kg = t >> 7, jl = t & 127;
  int j = w * 128 + jl;
  int k0 = kg * 128 + 2 * i;
  AP[g] = packh2(Ag[k0 * 512 + j], Ag[(k0 + 1) * 512 + j]);
}

// ------------------------------- GEMM --------------------------------------
// C[M,128-tile] = A[M,K] @ B  with B given transposed: Bt[n][k].
// Block 256 thr = 4 waves, each wave a 64x64 quadrant, 16x16x32 f16 MFMA.
// MODE 0: out f16 = val + bias0[n]   (U)
// MODE 1: n<256 -> loc = val + bias0[n] ; else scale = softplus(val + bias1[n-256])
template <int KDIM, int MODE>
__global__ __launch_bounds__(256, 2) void gemm_kernel(
    const f16* __restrict__ Ag, const f16* __restrict__ Bt,
    const float* __restrict__ bias0, const float* __restrict__ bias1,
    void* __restrict__ outp) {
  __shared__ f16 At[128 * 40];   // 32 k + 8 pad per row (bank-conflict-free b128)
  __shared__ f16 Bs[128 * 40];
  const int tid = threadIdx.x;
  const int m0 = blockIdx.y * 128;
  const int n0 = blockIdx.x * 128;
  const int w = tid >> 6, lane = tid & 63;
  const int wm = w & 1, wn = w >> 1;
  const int r = lane & 15, qd = lane >> 4;

  f32x4 zero4 = {0.f, 0.f, 0.f, 0.f};
  f32x4 acc[4][4];
#pragma unroll
  for (int mt = 0; mt < 4; ++mt)
#pragma unroll
    for (int nt = 0; nt < 4; ++nt) acc[mt][nt] = zero4;

  for (int kk = 0; kk < KDIM; kk += 32) {
#pragma unroll
    for (int s = 0; s < 2; ++s) {
      int fi = tid * 2 + s;
      int row = fi >> 2, q = fi & 3;
      float4 av = *(const float4*)(Ag + (size_t)(m0 + row) * KDIM + kk + q * 8);
      *(float4*)(At + row * 40 + q * 8) = av;
      float4 bv = *(const float4*)(Bt + (size_t)(n0 + row) * KDIM + kk + q * 8);
      *(float4*)(Bs + row * 40 + q * 8) = bv;
    }
    __syncthreads();
    f16x8 af[4], bf[4];
#pragma unroll
    for (int mt = 0; mt < 4; ++mt)
      af[mt] = *(const f16x8*)(At + (wm * 64 + mt * 16 + r) * 40 + qd * 8);
#pragma unroll
    for (int nt = 0; nt < 4; ++nt)
      bf[nt] = *(const f16x8*)(Bs + (wn * 64 + nt * 16 + r) * 40 + qd * 8);
#pragma unroll
    for (int mt = 0; mt < 4; ++mt)
#pragma unroll
      for (int nt = 0; nt < 4; ++nt)
        acc[mt][nt] = __builtin_amdgcn_mfma_f32_16x16x32_f16(af[mt], bf[nt],
                                                             acc[mt][nt], 0, 0, 0);
    __syncthreads();
  }

#pragma unroll
  for (int mt = 0; mt < 4; ++mt) {
#pragma unroll
    for (int nt = 0; nt < 4; ++nt) {
      int n = n0 + wn * 64 + nt * 16 + r;
#pragma unroll
      for (int i = 0; i < 4; ++i) {
        int m = m0 + wm * 64 + mt * 16 + qd * 4 + i;
        float v = acc[mt][nt][i];
        if (MODE == 0) {
          ((f16*)outp)[(size_t)m * NS + n] = (f16)(v + bias0[n]);
        } else {
          if (n < 256) {
            ((float*)outp)[(size_t)m * 256 + n] = v + bias0[n];
          } else {
            float z = v + bias1[n - 256];
            float sp = (z > 20.f) ? z : log1pf(__expf(z));
            ((float*)outp)[16777216ull + (size_t)m * 256 + (n - 256)] = sp;
          }
        }
      }
    }
  }
}

// ------------------------------- scan --------------------------------------
// 256 WGs: b = blk&63 (chain), w = blk>>6 (j-slice). All 4 WGs of a chain have
// the same blk%8 -> same XCD under round-robin (locality heuristic only; the
// protocol uses agent-scope atomics so correctness never depends on placement).
// Protocol: flag[b][w] = ts+1 published (release) after sbuf[par(ts+1)][b][w]
// holds WG w's segment of s_{ts+1}. Readers poll (relaxed) then acquire.
// Monotone flags + parity double-buffer: before WG w overwrites slot parity P
// at step ts, all peers had flag>=ts which implies they consumed s_{ts-1} (the
// previous occupant of P). Flags zeroed by hipMemsetAsync each launch.
__global__ __launch_bounds__(512, 2) void scan_kernel(
    const float4* __restrict__ AP4, const f16* __restrict__ U16,
    f16* __restrict__ S16, unsigned* __restrict__ sbuf,
    unsigned* __restrict__ flags, float* __restrict__ stout) {
  __shared__ float part[512];                  // [kg][jl] partials
  __shared__ __align__(16) unsigned sseg[256]; // s_ts packed f16x2, 4 segments
  const int t = threadIdx.x;
  const int b = (int)blockIdx.x & 63;
  const int w = (int)blockIdx.x >> 6;
  const int kg = t >> 7;

  // A slice: 16 float4 (64 VGPRs) per thread, resident across the whole loop
  float4 av[16];
#pragma unroll
  for (int c = 0; c < 16; ++c) av[c] = AP4[(size_t)(w * 512 + t) * 16 + c];

  if (t < 256) sseg[t] = 0u;                   // s_0 = 0

  const size_t urow0 = (size_t)b * 1024 * 512 + (size_t)w * 128;
  f16 uh = (f16)0.f;
  if (t < 128) uh = U16[urow0 + t];            // u_0
  __syncthreads();

#pragma unroll 1
  for (int ts = 0; ts < 1024; ++ts) {
    // ---- gather remote segments of s_ts (wave 2kg of each remote group) ----
    if (ts > 0 && kg != w && (t & 127) < 64) {
      const unsigned* flagp = flags + (unsigned)(b * 4 + kg) * 16;
      const unsigned tgt = (unsigned)ts;
      while (__hip_atomic_load(flagp, __ATOMIC_RELAXED,
                               __HIP_MEMORY_SCOPE_AGENT) < tgt) {}
      (void)__hip_atomic_load(flagp, __ATOMIC_ACQUIRE,
                              __HIP_MEMORY_SCOPE_AGENT);
      unsigned v = sbuf[(((unsigned)ts & 1) * 256 + b * 4 + kg) * 64 + (t & 63)];
      sseg[kg * 64 + (t & 63)] = v;
    }
    // prefetch next u (latency covered by this step's compute + sync)
    f16 un = uh;
    if (t < 128) {
      int nr = (ts < 1023) ? (ts + 1) : ts;
      un = U16[urow0 + (size_t)nr * 512 + t];
    }
    __syncthreads();   // B1: sseg complete

    // ---- partial dot: k in [kg*128, kg*128+128) against register A ----
    float a0 = 0.f, a1 = 0.f, a2 = 0.f, a3 = 0.f;
    const float4* sp4 = (const float4*)(sseg + kg * 64);
#pragma unroll
    for (int c = 0; c < 16; ++c) {
      float4 s4 = sp4[c];                      // wave-uniform LDS broadcast
      float4 ap = av[c];
      a0 = fdot2f(BCU(ap.x), BCU(s4.x), a0);
      a1 = fdot2f(BCU(ap.y), BCU(s4.y), a1);
      a2 = fdot2f(BCU(ap.z), BCU(s4.z), a2);
      a3 = fdot2f(BCU(ap.w), BCU(s4.w), a3);
    }
    part[t] = (a0 + a1) + (a2 + a3);           // t = kg*128+jl, stride-1 writes
    __syncthreads();   // B2: partials ready

    if (t < 128) {
      const size_t row = (size_t)b * 1024 + ts;
      float sum = (float)uh + ((part[t] + part[128 + t]) +
                               (part[256 + t] + part[384 + t]));
      float e = __expf(2.f * sum);
      float ns = 1.f - 2.f / (e + 1.f);        // tanh(sum)
      S16[row * 512 + w * 128 + t] = (f16)ns;  // new_state for loc/scale GEMM
      if (ts == 1022) stout[b * 512 + w * 128 + t] = ns;  // s_{1023}
      float pn = __shfl_xor(ns, 1, 64);
      if (!(t & 1)) {
        unsigned pk = packh2(ns, pn);
        sseg[w * 64 + (t >> 1)] = pk;          // own segment for next step
        sbuf[((((unsigned)ts + 1u) & 1) * 256 + b * 4 + w) * 64 + (t >> 1)] = pk;
      }
    }
    uh = un;
    __syncthreads();   // B3: drains vmcnt -> peers' sbuf stores are in L2
    if (t == 0)
      __hip_atomic_store(flags + (unsigned)(b * 4 + w) * 16,
                         (unsigned)(ts + 1), __ATOMIC_RELEASE,
                         __HIP_MEMORY_SCOPE_AGENT);
  }
}

// ------------------------------ launcher -----------------------------------

extern "C" void kernel_launch(void* const* d_in, const int* in_sizes, int n_in,
                              void* d_out, int out_size, void* d_ws, size_t ws_size,
                              hipStream_t stream) {
  (void)in_sizes; (void)n_in; (void)out_size; (void)ws_size;
  const float* xg  = (const float*)d_in[0];
  const float* Ag  = (const float*)d_in[1];
  const float* Bmg = (const float*)d_in[2];
  const float* bg  = (const float*)d_in[3];
  const float* Cg  = (const float*)d_in[4];
  const float* cg  = (const float*)d_in[5];
  const float* Dg  = (const float*)d_in[6];
  const float* dg  = (const float*)d_in[7];

  char* w = (char*)d_ws;
  f16* x16 = (f16*)(w + OFF_X16);
  f16* U16 = (f16*)(w + OFF_U16);
  f16* S16 = (f16*)(w + OFF_S16);
  f16* BmT = (f16*)(w + OFF_BMT);
  f16* CDT = (f16*)(w + OFF_CDT);
  unsigned* AP    = (unsigned*)(w + OFF_AP);
  unsigned* sbuf  = (unsigned*)(w + OFF_SBUF);
  unsigned* flags = (unsigned*)(w + OFF_FLAG);
  float* out = (float*)d_out;

  ck_x  <<<16384, 256, 0, stream>>>(xg, x16);
  ck_bmt<<<  512, 256, 0, stream>>>(Bmg, BmT);
  ck_cdt<<< 1024, 256, 0, stream>>>(Cg, Dg, CDT);
  ck_a  <<<  512, 256, 0, stream>>>(Ag, AP);
  hipMemsetAsync(w + OFF_FLAG, 0, 16384, stream);   // flags start at 0

  // U = x @ Bm + b
  gemm_kernel<256, 0><<<dim3(4, 512), 256, 0, stream>>>(x16, BmT, bg, nullptr,
                                                        (void*)U16);
  // sequential scan, 4 WGs per chain (overwrites x16 region with S16)
  scan_kernel<<<256, 512, 0, stream>>>((const float4*)AP, U16, S16, sbuf,
                                       flags, out + 33554432);
  // loc / softplus(scale) from S
  gemm_kernel<512, 1><<<dim3(4, 512), 256, 0, stream>>>(S16, CDT, cg, dg,
                                                        (void*)out);
}